// Round 3
// baseline (868.626 us; speedup 1.0000x reference)
//
#include <hip/hip_runtime.h>
#include <cstdint>
#include <cstddef>

typedef __bf16 bf16x8 __attribute__((ext_vector_type(8)));
typedef float  f32x4  __attribute__((ext_vector_type(4)));

#define MFMA16(a,b,c) __builtin_amdgcn_mfma_f32_16x16x32_bf16((a),(b),(c),0,0,0)

// ---------- helpers ----------
__device__ __forceinline__ uint f2bf1(float f){
  uint u = __builtin_bit_cast(uint, f);
  u += 0x7FFFu + ((u >> 16) & 1u);   // RNE to bf16
  return u >> 16;
}
__device__ __forceinline__ uint pack2(float a, float b){  // RNE (cold paths)
  return f2bf1(a) | (f2bf1(b) << 16);
}
// fast pack: round-half-away via biased add + v_perm_b32 (3 VALU ops)
__device__ __forceinline__ uint pack2f(float a, float b){
  uint ua = __builtin_bit_cast(uint, a) + 0x8000u;
  uint ub = __builtin_bit_cast(uint, b) + 0x8000u;
  return __builtin_amdgcn_perm(ub, ua, 0x07060302u); // {ua.b2,ua.b3,ub.b2,ub.b3}
}
__device__ __forceinline__ float bflo(uint d){ return __builtin_bit_cast(float, d << 16); }
__device__ __forceinline__ float bfhi(uint d){ return __builtin_bit_cast(float, d & 0xFFFF0000u); }

// =====================================================================
// Kernel 1: transpose triplane (B,3,C,H,W) fp32 -> (B,3,H,W,C) bf16
// =====================================================================
__global__ __launch_bounds__(256, 4) void transpose_k(
    const float* __restrict__ tri, ushort* __restrict__ tp)
{
  __shared__ ushort st[64 * 41];
  const int bi  = blockIdx.x;
  const int xb  = bi & 3;
  const int y   = (bi >> 2) & 255;
  const int q   = bi >> 10;            // b*3+pl, 0..11
  const int tid = threadIdx.x;
  const float* src = tri + (size_t)q * 40 * 65536 + y * 256 + xb * 64;
#pragma unroll
  for (int it = 0; it < 10; it++){
    int lin = it * 256 + tid;          // 0..2559
    int c = lin >> 6, x = lin & 63;
    float v = src[(size_t)c * 65536 + x];
    st[x * 41 + c] = (ushort)f2bf1(v);
  }
  __syncthreads();
  uint* dst = (uint*)(tp + ((size_t)q * 65536 + (size_t)y * 256 + xb * 64) * 40);
#pragma unroll
  for (int it = 0; it < 5; it++){
    int lin = it * 256 + tid;          // dword index 0..1279
    int e  = lin * 2;
    int x1 = (e * 1639) >> 16;       int c1 = e  - x1 * 40;
    int e2 = e + 1;
    int x2 = (e2 * 1639) >> 16;      int c2 = e2 - x2 * 40;
    dst[lin] = (uint)st[x1 * 41 + c1] | ((uint)st[x2 * 41 + c2] << 16);
  }
}

// =====================================================================
// Kernel 2: pack weights into MFMA A-fragment order (unchanged)
// sections (uint4 offsets): 0 dw1T,2048 cw1T,4096 w2dT,6144 w2cT,8192 w3dT,8448 w3cT
// =====================================================================
__global__ void pack_k(const float* __restrict__ dw1, const float* __restrict__ cw1,
                       const float* __restrict__ dw2, const float* __restrict__ cw2,
                       const float* __restrict__ dw3, const float* __restrict__ cw3,
                       uint4* __restrict__ wpk)
{
  int idx = blockIdx.x * 256 + threadIdx.x;
  if (idx >= 8704) return;
  int mode, rel;
  if      (idx < 2048){ mode = 0; rel = idx; }
  else if (idx < 4096){ mode = 1; rel = idx - 2048; }
  else if (idx < 6144){ mode = 2; rel = idx - 4096; }
  else if (idx < 8192){ mode = 3; rel = idx - 6144; }
  else if (idx < 8448){ mode = 4; rel = idx - 8192; }
  else                { mode = 5; rel = idx - 8448; }
  int frag = rel >> 6, lane = rel & 63;
  int Mt = frag >> 2, s = frag & 3;
  int m  = Mt * 16 + (lane & 15);
  int kb = s * 32 + (lane >> 4) * 8;
  uint d[4];
#pragma unroll
  for (int jj = 0; jj < 4; jj++){
    float v0 = 0.f, v1 = 0.f;
#pragma unroll
    for (int h = 0; h < 2; h++){
      int k = kb + jj * 2 + h;
      float v = 0.f;
      switch (mode){
        case 0: v = (k < 120) ? dw1[k * 128 + m] : 0.f; break;
        case 1: v = (k < 123) ? cw1[k * 128 + m] : 0.f; break;
        case 2: v = dw2[k * 128 + m]; break;
        case 3: v = cw2[k * 128 + m]; break;
        case 4: v = (m == 0) ? dw3[k] : 0.f; break;
        default: v = (m >= 1 && m <= 3) ? cw3[k * 3 + (m - 1)] : 0.f; break;
      }
      if (h == 0) v0 = v; else v1 = v;
    }
    d[jj] = pack2(v0, v1);
  }
  uint4 o; o.x = d[0]; o.y = d[1]; o.z = d[2]; o.w = d[3];
  wpk[idx] = o;
}

// =====================================================================
// Kernel 3: FUSED gather + MLP — register-pressure-shaped (no spills):
//  - layer1 in two Mt-halves (64 live acc regs)
//  - dense layers per t-pair, in-place LDS update (64 acc, 16 bh regs)
//  - fast 3-op bf16 pack
// =====================================================================
__device__ __forceinline__ uint4 blend4(uint4 a, uint4 b, uint4 c, uint4 d,
                                        float w00, float w10, float w01, float w11){
  uint4 ov;
  ov.x = pack2f(w00*bflo(a.x)+w10*bflo(b.x)+w01*bflo(c.x)+w11*bflo(d.x),
                w00*bfhi(a.x)+w10*bfhi(b.x)+w01*bfhi(c.x)+w11*bfhi(d.x));
  ov.y = pack2f(w00*bflo(a.y)+w10*bflo(b.y)+w01*bflo(c.y)+w11*bflo(d.y),
                w00*bfhi(a.y)+w10*bfhi(b.y)+w01*bfhi(c.y)+w11*bfhi(d.y));
  ov.z = pack2f(w00*bflo(a.z)+w10*bflo(b.z)+w01*bflo(c.z)+w11*bflo(d.z),
                w00*bfhi(a.z)+w10*bfhi(b.z)+w01*bfhi(c.z)+w11*bfhi(d.z));
  ov.w = pack2f(w00*bflo(a.w)+w10*bflo(b.w)+w01*bflo(c.w)+w11*bflo(d.w),
                w00*bfhi(a.w)+w10*bfhi(b.w)+w01*bfhi(c.w)+w11*bfhi(d.w));
  return ov;
}

__device__ __forceinline__ bf16x8 read_h(const uint* S, int s, int t, int lrow, int lq){
  int dwb = (s * 16 + lq * 4) ^ ((lrow & 7) << 2);
  return __builtin_bit_cast(bf16x8, *(const uint4*)&S[(t * 16 + lrow) * 64 + dwb]);
}

__device__ __forceinline__ void put_h(uint* S, f32x4 v, int Mt, int t, int lrow, int lq){
  uint2 w;
  w.x = pack2f(fmaxf(v[0], 0.f), fmaxf(v[1], 0.f));
  w.y = pack2f(fmaxf(v[2], 0.f), fmaxf(v[3], 0.f));
  int dw = (Mt * 8 + lq * 2) ^ ((lrow & 7) << 2);
  *(uint2*)&S[(t * 16 + lrow) * 64 + dw] = w;
}

// layer1 half: hidden units [Mh*64, Mh*64+64) for all 4 t-tiles
__device__ __forceinline__ void l1_half(uint* S, const uint4* __restrict__ W,
                                        const float* __restrict__ bias,
                                        const uint4 (&bf)[4][4], int Mh,
                                        int lrow, int lq, int lane){
  f32x4 acc[4][4];
#pragma unroll
  for (int Mi = 0; Mi < 4; Mi++){
    f32x4 bi = *(const f32x4*)(bias + (Mh * 4 + Mi) * 16 + lq * 4);
#pragma unroll
    for (int t = 0; t < 4; t++) acc[Mi][t] = bi;
  }
#pragma unroll
  for (int s = 0; s < 4; s++)
#pragma unroll
    for (int Mi = 0; Mi < 4; Mi++){
      bf16x8 aw = __builtin_bit_cast(bf16x8, W[((Mh * 4 + Mi) * 4 + s) * 64 + lane]);
#pragma unroll
      for (int t = 0; t < 4; t++)
        acc[Mi][t] = MFMA16(aw, __builtin_bit_cast(bf16x8, bf[s][t]), acc[Mi][t]);
    }
#pragma unroll
  for (int Mi = 0; Mi < 4; Mi++)
#pragma unroll
    for (int t = 0; t < 4; t++)
      put_h(S, acc[Mi][t], Mh * 4 + Mi, t, lrow, lq);
}

// dense layer: per t-pair, read h rows, MFMA, write h' back IN PLACE.
// Safe: each t-pair's rows are read completely before being overwritten,
// and different t-pairs touch disjoint rows (wave-private LDS).
__device__ __forceinline__ void dense_l(uint* S, const uint4* __restrict__ W,
                                        const float* __restrict__ bias,
                                        int lrow, int lq, int lane){
#pragma unroll
  for (int tp = 0; tp < 2; tp++){
    f32x4 acc[8][2];
#pragma unroll
    for (int Mt = 0; Mt < 8; Mt++){
      f32x4 bi = *(const f32x4*)(bias + Mt * 16 + lq * 4);
      acc[Mt][0] = bi; acc[Mt][1] = bi;
    }
#pragma unroll
    for (int s = 0; s < 4; s++){
      bf16x8 bh0 = read_h(S, s, 2 * tp + 0, lrow, lq);
      bf16x8 bh1 = read_h(S, s, 2 * tp + 1, lrow, lq);
#pragma unroll
      for (int Mt = 0; Mt < 8; Mt++){
        bf16x8 aw = __builtin_bit_cast(bf16x8, W[(Mt * 4 + s) * 64 + lane]);
        acc[Mt][0] = MFMA16(aw, bh0, acc[Mt][0]);
        acc[Mt][1] = MFMA16(aw, bh1, acc[Mt][1]);
      }
    }
#pragma unroll
    for (int Mt = 0; Mt < 8; Mt++){
      put_h(S, acc[Mt][0], Mt, 2 * tp + 0, lrow, lq);
      put_h(S, acc[Mt][1], Mt, 2 * tp + 1, lrow, lq);
    }
  }
}

__device__ __forceinline__ void out_l(const uint* S, const uint4* __restrict__ W,
                                      f32x4 (&acc3)[4], int lrow, int lq, int lane){
#pragma unroll
  for (int s = 0; s < 4; s++){
    bf16x8 aw = __builtin_bit_cast(bf16x8, W[s * 64 + lane]);
#pragma unroll
    for (int t = 0; t < 4; t++){
      bf16x8 bh = read_h(S, s, t, lrow, lq);
      acc3[t] = MFMA16(aw, bh, acc3[t]);
    }
  }
}

__global__ __launch_bounds__(256, 2) void fused_k(
    const ushort* __restrict__ tp, const float* __restrict__ coords,
    const float* __restrict__ vdirs, const uint4* __restrict__ wpk,
    const float* __restrict__ db1, const float* __restrict__ db2,
    const float* __restrict__ db3, const float* __restrict__ cb1,
    const float* __restrict__ cb2, const float* __restrict__ cb3,
    float* __restrict__ out)
{
  __shared__ uint4 sS4[4096];   // 64 KB: 4 waves x 16 KB private
  const int wave = threadIdx.x >> 6;
  uint* S = (uint*)sS4 + wave * 4096;
  const int lane = threadIdx.x & 63, lrow = lane & 15, lq = lane >> 4;
  const int ptw = blockIdx.x * 256 + wave * 64;

  // ---- fused gather: build B-frags directly in registers ----
  uint4 bf[4][4];
#pragma unroll
  for (int t = 0; t < 4; t++){
    const int p  = ptw + t * 16 + lrow;
    const int bb = p >> 18;                          // N = 2^18
    const float cx = coords[3 * p], cy = coords[3 * p + 1], cz = coords[3 * p + 2];
    float pw00[3], pw10[3], pw01[3], pw11[3];
    uint  o00[3], o10[3], o01[3], o11[3];
#pragma unroll
    for (int pl = 0; pl < 3; pl++){
      const float u = (pl == 2) ? cy : cx;
      const float v = (pl == 0) ? cy : cz;
      float ix = fmaf(u, 128.f, 127.5f);
      float iy = fmaf(v, 128.f, 127.5f);
      float fx0 = floorf(ix), fy0 = floorf(iy);
      float fx = ix - fx0, fy = iy - fy0;
      int x0 = (int)fx0, y0 = (int)fy0;
      float wx0 = (x0 >= 0  && x0 < 256) ? (1.f - fx) : 0.f;
      float wx1 = (x0 >= -1 && x0 < 255) ? fx : 0.f;
      float wy0 = (y0 >= 0  && y0 < 256) ? (1.f - fy) : 0.f;
      float wy1 = (y0 >= -1 && y0 < 255) ? fy : 0.f;
      int xc0 = min(max(x0, 0), 255), xc1 = min(max(x0 + 1, 0), 255);
      int yc0 = min(max(y0, 0), 255), yc1 = min(max(y0 + 1, 0), 255);
      pw00[pl] = wx0 * wy0; pw10[pl] = wx1 * wy0;
      pw01[pl] = wx0 * wy1; pw11[pl] = wx1 * wy1;
      o00[pl] = ((uint)yc0 * 256u + (uint)xc0) * 40u;
      o10[pl] = ((uint)yc0 * 256u + (uint)xc1) * 40u;
      o01[pl] = ((uint)yc1 * 256u + (uint)xc0) * 40u;
      o11[pl] = ((uint)yc1 * 256u + (uint)xc1) * 40u;
    }
#pragma unroll
    for (int s = 0; s < 4; s++){
      const int chunk = s * 4 + lq;        // channel chunk = [chunk*8, chunk*8+7]
      if (chunk == 15){                    // vd + pad (only lq==3, s==3)
        const float v0 = vdirs[3 * p], v1 = vdirs[3 * p + 1], v2 = vdirs[3 * p + 2];
        uint4 tt; tt.x = pack2f(v0, v1); tt.y = pack2f(v2, 0.f); tt.z = 0u; tt.w = 0u;
        bf[s][t] = tt;
      } else {
        const int pl = (chunk < 5) ? 0 : (chunk < 10) ? 1 : 2;
        const int c0 = chunk * 8 - pl * 40;   // local channel offset in plane row
        const ushort* base = tp + (size_t)(bb * 3 + pl) * 2621440 + c0;
        uint4 a = *(const uint4*)(base + o00[pl]);
        uint4 b = *(const uint4*)(base + o10[pl]);
        uint4 c = *(const uint4*)(base + o01[pl]);
        uint4 d = *(const uint4*)(base + o11[pl]);
        bf[s][t] = blend4(a, b, c, d, pw00[pl], pw10[pl], pw01[pl], pw11[pl]);
      }
    }
  }

  // ---- MLP ----
  f32x4 acc3[4];
  {
    float i0 = (lq == 0) ? db3[0] : 0.f;
    float i1 = (lq == 0) ? cb3[0] : 0.f;
    float i2 = (lq == 0) ? cb3[1] : 0.f;
    float i3 = (lq == 0) ? cb3[2] : 0.f;
    f32x4 iv = {i0, i1, i2, i3};
#pragma unroll
    for (int t = 0; t < 4; t++) acc3[t] = iv;
  }

  // density path
  l1_half(S, wpk + 0,    db1, bf, 0, lrow, lq, lane);
  l1_half(S, wpk + 0,    db1, bf, 1, lrow, lq, lane);
  dense_l(S, wpk + 4096, db2,        lrow, lq, lane);
  out_l (S, wpk + 8192, acc3,       lrow, lq, lane);
  // color path
  l1_half(S, wpk + 2048, cb1, bf, 0, lrow, lq, lane);
  l1_half(S, wpk + 2048, cb1, bf, 1, lrow, lq, lane);
  dense_l(S, wpk + 6144, cb2,        lrow, lq, lane);
  out_l (S, wpk + 8448, acc3,       lrow, lq, lane);

  if (lq == 0){
#pragma unroll
    for (int t = 0; t < 4; t++){
      int p = ptw + t * 16 + lrow;
      out[p] = acc3[t][0];
      float* rgb = out + 1048576 + (size_t)p * 3;
      rgb[0] = 1.f / (1.f + __expf(-acc3[t][1]));
      rgb[1] = 1.f / (1.f + __expf(-acc3[t][2]));
      rgb[2] = 1.f / (1.f + __expf(-acc3[t][3]));
    }
  }
}

// =====================================================================
extern "C" void kernel_launch(void* const* d_in, const int* in_sizes, int n_in,
                              void* d_out, int out_size, void* d_ws, size_t ws_size,
                              hipStream_t stream)
{
  (void)in_sizes; (void)n_in; (void)out_size; (void)ws_size;
  const float* tri    = (const float*)d_in[0];
  const float* coords = (const float*)d_in[1];
  const float* vdirs  = (const float*)d_in[2];
  const float* dw1 = (const float*)d_in[3];  const float* db1 = (const float*)d_in[4];
  const float* dw2 = (const float*)d_in[5];  const float* db2 = (const float*)d_in[6];
  const float* dw3 = (const float*)d_in[7];  const float* db3 = (const float*)d_in[8];
  const float* cw1 = (const float*)d_in[9];  const float* cb1 = (const float*)d_in[10];
  const float* cw2 = (const float*)d_in[11]; const float* cb2 = (const float*)d_in[12];
  const float* cw3 = (const float*)d_in[13]; const float* cb3 = (const float*)d_in[14];

  char* ws = (char*)d_ws;
  const size_t planes_bytes = 62914560;   // 4*3*256*256*40*2
  ushort* tp  = (ushort*)ws;
  uint4*  wpk = (uint4*)(ws + planes_bytes);

  transpose_k<<<12288, 256, 0, stream>>>(tri, tp);
  pack_k<<<34, 256, 0, stream>>>(dw1, cw1, dw2, cw2, dw3, cw3, wpk);
  fused_k<<<4096, 256, 0, stream>>>(tp, coords, vdirs, wpk,
                                    db1, db2, db3, cb1, cb2, cb3,
                                    (float*)d_out);
}

// Round 4
// 733.217 us; speedup vs baseline: 1.1847x; 1.1847x over previous
//
#include <hip/hip_runtime.h>
#include <cstdint>
#include <cstddef>

typedef __bf16 bf16x8 __attribute__((ext_vector_type(8)));
typedef float  f32x4  __attribute__((ext_vector_type(4)));

#define MFMA16(a,b,c) __builtin_amdgcn_mfma_f32_16x16x32_bf16((a),(b),(c),0,0,0)

// ---------- helpers ----------
__device__ __forceinline__ uint f2bf1(float f){
  uint u = __builtin_bit_cast(uint, f);
  u += 0x7FFFu + ((u >> 16) & 1u);   // RNE to bf16
  return u >> 16;
}
__device__ __forceinline__ uint pack2(float a, float b){  // RNE (cold paths)
  return f2bf1(a) | (f2bf1(b) << 16);
}
// fast pack: round-half-away via biased add + v_perm_b32 (3 VALU ops)
__device__ __forceinline__ uint pack2f(float a, float b){
  uint ua = __builtin_bit_cast(uint, a) + 0x8000u;
  uint ub = __builtin_bit_cast(uint, b) + 0x8000u;
  return __builtin_amdgcn_perm(ub, ua, 0x07060302u); // {ua.b2,ua.b3,ub.b2,ub.b3}
}
__device__ __forceinline__ float bflo(uint d){ return __builtin_bit_cast(float, d << 16); }
__device__ __forceinline__ float bfhi(uint d){ return __builtin_bit_cast(float, d & 0xFFFF0000u); }

// =====================================================================
// Kernel 1: transpose triplane (B,3,C,H,W) fp32 -> (B,3,H,W,C) bf16
// =====================================================================
__global__ __launch_bounds__(256, 4) void transpose_k(
    const float* __restrict__ tri, ushort* __restrict__ tp)
{
  __shared__ ushort st[64 * 41];
  const int bi  = blockIdx.x;
  const int xb  = bi & 3;
  const int y   = (bi >> 2) & 255;
  const int q   = bi >> 10;            // b*3+pl, 0..11
  const int tid = threadIdx.x;
  const float* src = tri + (size_t)q * 40 * 65536 + y * 256 + xb * 64;
#pragma unroll
  for (int it = 0; it < 10; it++){
    int lin = it * 256 + tid;          // 0..2559
    int c = lin >> 6, x = lin & 63;
    float v = src[(size_t)c * 65536 + x];
    st[x * 41 + c] = (ushort)f2bf1(v);
  }
  __syncthreads();
  uint* dst = (uint*)(tp + ((size_t)q * 65536 + (size_t)y * 256 + xb * 64) * 40);
#pragma unroll
  for (int it = 0; it < 5; it++){
    int lin = it * 256 + tid;          // dword index 0..1279
    int e  = lin * 2;
    int x1 = (e * 1639) >> 16;       int c1 = e  - x1 * 40;
    int e2 = e + 1;
    int x2 = (e2 * 1639) >> 16;      int c2 = e2 - x2 * 40;
    dst[lin] = (uint)st[x1 * 41 + c1] | ((uint)st[x2 * 41 + c2] << 16);
  }
}

// =====================================================================
// Kernel 2: pack weights into MFMA A-fragment order (unchanged)
// sections (uint4 offsets): 0 dw1T,2048 cw1T,4096 w2dT,6144 w2cT,8192 w3dT,8448 w3cT
// =====================================================================
__global__ void pack_k(const float* __restrict__ dw1, const float* __restrict__ cw1,
                       const float* __restrict__ dw2, const float* __restrict__ cw2,
                       const float* __restrict__ dw3, const float* __restrict__ cw3,
                       uint4* __restrict__ wpk)
{
  int idx = blockIdx.x * 256 + threadIdx.x;
  if (idx >= 8704) return;
  int mode, rel;
  if      (idx < 2048){ mode = 0; rel = idx; }
  else if (idx < 4096){ mode = 1; rel = idx - 2048; }
  else if (idx < 6144){ mode = 2; rel = idx - 4096; }
  else if (idx < 8192){ mode = 3; rel = idx - 6144; }
  else if (idx < 8448){ mode = 4; rel = idx - 8192; }
  else                { mode = 5; rel = idx - 8448; }
  int frag = rel >> 6, lane = rel & 63;
  int Mt = frag >> 2, s = frag & 3;
  int m  = Mt * 16 + (lane & 15);
  int kb = s * 32 + (lane >> 4) * 8;
  uint d[4];
#pragma unroll
  for (int jj = 0; jj < 4; jj++){
    float v0 = 0.f, v1 = 0.f;
#pragma unroll
    for (int h = 0; h < 2; h++){
      int k = kb + jj * 2 + h;
      float v = 0.f;
      switch (mode){
        case 0: v = (k < 120) ? dw1[k * 128 + m] : 0.f; break;
        case 1: v = (k < 123) ? cw1[k * 128 + m] : 0.f; break;
        case 2: v = dw2[k * 128 + m]; break;
        case 3: v = cw2[k * 128 + m]; break;
        case 4: v = (m == 0) ? dw3[k] : 0.f; break;
        default: v = (m >= 1 && m <= 3) ? cw3[k * 3 + (m - 1)] : 0.f; break;
      }
      if (h == 0) v0 = v; else v1 = v;
    }
    d[jj] = pack2(v0, v1);
  }
  uint4 o; o.x = d[0]; o.y = d[1]; o.z = d[2]; o.w = d[3];
  wpk[idx] = o;
}

// =====================================================================
// Kernel 3: FUSED gather + MLP, 32 points/wave (t=2).
// Register budget (the R2/R3 spill fix): bf[4][2]=32 VGPR, acc[8][2]=64
// (AGPR-eligible), peak unified demand ~160 < 256 @ launch_bounds(256,2).
// LDS: 8 KB/wave (32 rows x 256 B), wave-private, XOR-swizzled.
// Batch<->XCD affinity: batch = blockIdx&3 so each XCD's L2 caches one
// batch's planes (15.7 MB) instead of all four (63 MB).
// =====================================================================
__device__ __forceinline__ uint4 blend4(uint4 a, uint4 b, uint4 c, uint4 d,
                                        float w00, float w10, float w01, float w11){
  uint4 ov;
  ov.x = pack2f(w00*bflo(a.x)+w10*bflo(b.x)+w01*bflo(c.x)+w11*bflo(d.x),
                w00*bfhi(a.x)+w10*bfhi(b.x)+w01*bfhi(c.x)+w11*bfhi(d.x));
  ov.y = pack2f(w00*bflo(a.y)+w10*bflo(b.y)+w01*bflo(c.y)+w11*bflo(d.y),
                w00*bfhi(a.y)+w10*bfhi(b.y)+w01*bfhi(c.y)+w11*bfhi(d.y));
  ov.z = pack2f(w00*bflo(a.z)+w10*bflo(b.z)+w01*bflo(c.z)+w11*bflo(d.z),
                w00*bfhi(a.z)+w10*bfhi(b.z)+w01*bfhi(c.z)+w11*bfhi(d.z));
  ov.w = pack2f(w00*bflo(a.w)+w10*bflo(b.w)+w01*bflo(c.w)+w11*bflo(d.w),
                w00*bfhi(a.w)+w10*bfhi(b.w)+w01*bfhi(c.w)+w11*bfhi(d.w));
  return ov;
}

__device__ __forceinline__ bf16x8 read_h(const uint* S, int s, int t, int lrow, int lq){
  int dwb = (s * 16 + lq * 4) ^ ((lrow & 7) << 2);
  return __builtin_bit_cast(bf16x8, *(const uint4*)&S[(t * 16 + lrow) * 64 + dwb]);
}

__device__ __forceinline__ void put_h(uint* S, f32x4 v, int Mt, int t, int lrow, int lq){
  uint2 w;
  w.x = pack2f(fmaxf(v[0], 0.f), fmaxf(v[1], 0.f));
  w.y = pack2f(fmaxf(v[2], 0.f), fmaxf(v[3], 0.f));
  int dw = (Mt * 8 + lq * 2) ^ ((lrow & 7) << 2);
  *(uint2*)&S[(t * 16 + lrow) * 64 + dw] = w;
}

__device__ __forceinline__ void layer1(uint* S, const uint4* __restrict__ W,
                                       const float* __restrict__ bias,
                                       const uint4 (&bf)[4][2],
                                       int lrow, int lq, int lane){
  f32x4 acc[8][2];
#pragma unroll
  for (int Mt = 0; Mt < 8; Mt++){
    f32x4 bi = *(const f32x4*)(bias + Mt * 16 + lq * 4);
    acc[Mt][0] = bi; acc[Mt][1] = bi;
  }
#pragma unroll
  for (int s = 0; s < 4; s++)
#pragma unroll
    for (int Mt = 0; Mt < 8; Mt++){
      bf16x8 aw = __builtin_bit_cast(bf16x8, W[(Mt * 4 + s) * 64 + lane]);
      acc[Mt][0] = MFMA16(aw, __builtin_bit_cast(bf16x8, bf[s][0]), acc[Mt][0]);
      acc[Mt][1] = MFMA16(aw, __builtin_bit_cast(bf16x8, bf[s][1]), acc[Mt][1]);
    }
#pragma unroll
  for (int Mt = 0; Mt < 8; Mt++){
    put_h(S, acc[Mt][0], Mt, 0, lrow, lq);
    put_h(S, acc[Mt][1], Mt, 1, lrow, lq);
  }
}

// dense layer: read h rows, MFMA, write h' back IN PLACE (DS pipe is
// in-order per wave; all reads issue before the writes).
__device__ __forceinline__ void dense_l(uint* S, const uint4* __restrict__ W,
                                        const float* __restrict__ bias,
                                        int lrow, int lq, int lane){
  f32x4 acc[8][2];
#pragma unroll
  for (int Mt = 0; Mt < 8; Mt++){
    f32x4 bi = *(const f32x4*)(bias + Mt * 16 + lq * 4);
    acc[Mt][0] = bi; acc[Mt][1] = bi;
  }
#pragma unroll
  for (int s = 0; s < 4; s++){
    bf16x8 bh0 = read_h(S, s, 0, lrow, lq);
    bf16x8 bh1 = read_h(S, s, 1, lrow, lq);
#pragma unroll
    for (int Mt = 0; Mt < 8; Mt++){
      bf16x8 aw = __builtin_bit_cast(bf16x8, W[(Mt * 4 + s) * 64 + lane]);
      acc[Mt][0] = MFMA16(aw, bh0, acc[Mt][0]);
      acc[Mt][1] = MFMA16(aw, bh1, acc[Mt][1]);
    }
  }
#pragma unroll
  for (int Mt = 0; Mt < 8; Mt++){
    put_h(S, acc[Mt][0], Mt, 0, lrow, lq);
    put_h(S, acc[Mt][1], Mt, 1, lrow, lq);
  }
}

__device__ __forceinline__ void out_l(const uint* S, const uint4* __restrict__ W,
                                      f32x4 (&acc3)[2], int lrow, int lq, int lane){
#pragma unroll
  for (int s = 0; s < 4; s++){
    bf16x8 aw = __builtin_bit_cast(bf16x8, W[s * 64 + lane]);
    acc3[0] = MFMA16(aw, read_h(S, s, 0, lrow, lq), acc3[0]);
    acc3[1] = MFMA16(aw, read_h(S, s, 1, lrow, lq), acc3[1]);
  }
}

__global__ __launch_bounds__(256, 2) void fused_k(
    const ushort* __restrict__ tp, const float* __restrict__ coords,
    const float* __restrict__ vdirs, const uint4* __restrict__ wpk,
    const float* __restrict__ db1, const float* __restrict__ db2,
    const float* __restrict__ db3, const float* __restrict__ cb1,
    const float* __restrict__ cb2, const float* __restrict__ cb3,
    float* __restrict__ out)
{
  __shared__ uint4 sS4[2048];   // 32 KB: 4 waves x 8 KB private
  const int wave = threadIdx.x >> 6;
  uint* S = (uint*)sS4 + wave * 2048;
  const int lane = threadIdx.x & 63, lrow = lane & 15, lq = lane >> 4;
  // batch<->XCD affinity swizzle: batch = blk&3 (XCD = blk%8 typically)
  const int blk   = blockIdx.x;                 // 0..8191
  const int pbase = (blk & 3) * 262144 + (blk >> 2) * 128 + wave * 32;

  // ---- fused gather: build B-frags directly in registers ----
  uint4 bf[4][2];
#pragma unroll
  for (int t = 0; t < 2; t++){
    const int p  = pbase + t * 16 + lrow;
    const int bb = p >> 18;                          // N = 2^18
    const float cx = coords[3 * p], cy = coords[3 * p + 1], cz = coords[3 * p + 2];
    float pw00[3], pw10[3], pw01[3], pw11[3];
    uint  o00[3], o10[3], o01[3], o11[3];
#pragma unroll
    for (int pl = 0; pl < 3; pl++){
      const float u = (pl == 2) ? cy : cx;
      const float v = (pl == 0) ? cy : cz;
      float ix = fmaf(u, 128.f, 127.5f);
      float iy = fmaf(v, 128.f, 127.5f);
      float fx0 = floorf(ix), fy0 = floorf(iy);
      float fx = ix - fx0, fy = iy - fy0;
      int x0 = (int)fx0, y0 = (int)fy0;
      float wx0 = (x0 >= 0  && x0 < 256) ? (1.f - fx) : 0.f;
      float wx1 = (x0 >= -1 && x0 < 255) ? fx : 0.f;
      float wy0 = (y0 >= 0  && y0 < 256) ? (1.f - fy) : 0.f;
      float wy1 = (y0 >= -1 && y0 < 255) ? fy : 0.f;
      int xc0 = min(max(x0, 0), 255), xc1 = min(max(x0 + 1, 0), 255);
      int yc0 = min(max(y0, 0), 255), yc1 = min(max(y0 + 1, 0), 255);
      pw00[pl] = wx0 * wy0; pw10[pl] = wx1 * wy0;
      pw01[pl] = wx0 * wy1; pw11[pl] = wx1 * wy1;
      o00[pl] = ((uint)yc0 * 256u + (uint)xc0) * 40u;
      o10[pl] = ((uint)yc0 * 256u + (uint)xc1) * 40u;
      o01[pl] = ((uint)yc1 * 256u + (uint)xc0) * 40u;
      o11[pl] = ((uint)yc1 * 256u + (uint)xc1) * 40u;
    }
#pragma unroll
    for (int s = 0; s < 4; s++){
      const int chunk = s * 4 + lq;        // channel chunk = [chunk*8, chunk*8+7]
      if (chunk == 15){                    // vd + pad (only lq==3, s==3)
        const float v0 = vdirs[3 * p], v1 = vdirs[3 * p + 1], v2 = vdirs[3 * p + 2];
        uint4 tt; tt.x = pack2f(v0, v1); tt.y = pack2f(v2, 0.f); tt.z = 0u; tt.w = 0u;
        bf[s][t] = tt;
      } else {
        const int pl = (chunk < 5) ? 0 : (chunk < 10) ? 1 : 2;
        const int c0 = chunk * 8 - pl * 40;   // local channel offset in plane row
        const ushort* base = tp + (size_t)(bb * 3 + pl) * 2621440 + c0;
        uint4 a = *(const uint4*)(base + o00[pl]);
        uint4 b = *(const uint4*)(base + o10[pl]);
        uint4 c = *(const uint4*)(base + o01[pl]);
        uint4 d = *(const uint4*)(base + o11[pl]);
        bf[s][t] = blend4(a, b, c, d, pw00[pl], pw10[pl], pw01[pl], pw11[pl]);
      }
    }
  }

  // ---- MLP ----
  f32x4 acc3[2];
  {
    float i0 = (lq == 0) ? db3[0] : 0.f;
    float i1 = (lq == 0) ? cb3[0] : 0.f;
    float i2 = (lq == 0) ? cb3[1] : 0.f;
    float i3 = (lq == 0) ? cb3[2] : 0.f;
    f32x4 iv = {i0, i1, i2, i3};
    acc3[0] = iv; acc3[1] = iv;
  }

  // density path
  layer1 (S, wpk + 0,    db1, bf, lrow, lq, lane);
  dense_l(S, wpk + 4096, db2,     lrow, lq, lane);
  out_l  (S, wpk + 8192, acc3,    lrow, lq, lane);
  // color path
  layer1 (S, wpk + 2048, cb1, bf, lrow, lq, lane);
  dense_l(S, wpk + 6144, cb2,     lrow, lq, lane);
  out_l  (S, wpk + 8448, acc3,    lrow, lq, lane);

  if (lq == 0){
#pragma unroll
    for (int t = 0; t < 2; t++){
      int p = pbase + t * 16 + lrow;
      out[p] = acc3[t][0];
      float* rgb = out + 1048576 + (size_t)p * 3;
      rgb[0] = 1.f / (1.f + __expf(-acc3[t][1]));
      rgb[1] = 1.f / (1.f + __expf(-acc3[t][2]));
      rgb[2] = 1.f / (1.f + __expf(-acc3[t][3]));
    }
  }
}

// =====================================================================
extern "C" void kernel_launch(void* const* d_in, const int* in_sizes, int n_in,
                              void* d_out, int out_size, void* d_ws, size_t ws_size,
                              hipStream_t stream)
{
  (void)in_sizes; (void)n_in; (void)out_size; (void)ws_size;
  const float* tri    = (const float*)d_in[0];
  const float* coords = (const float*)d_in[1];
  const float* vdirs  = (const float*)d_in[2];
  const float* dw1 = (const float*)d_in[3];  const float* db1 = (const float*)d_in[4];
  const float* dw2 = (const float*)d_in[5];  const float* db2 = (const float*)d_in[6];
  const float* dw3 = (const float*)d_in[7];  const float* db3 = (const float*)d_in[8];
  const float* cw1 = (const float*)d_in[9];  const float* cb1 = (const float*)d_in[10];
  const float* cw2 = (const float*)d_in[11]; const float* cb2 = (const float*)d_in[12];
  const float* cw3 = (const float*)d_in[13]; const float* cb3 = (const float*)d_in[14];

  char* ws = (char*)d_ws;
  const size_t planes_bytes = 62914560;   // 4*3*256*256*40*2
  ushort* tp  = (ushort*)ws;
  uint4*  wpk = (uint4*)(ws + planes_bytes);

  transpose_k<<<12288, 256, 0, stream>>>(tri, tp);
  pack_k<<<34, 256, 0, stream>>>(dw1, cw1, dw2, cw2, dw3, cw3, wpk);
  fused_k<<<8192, 256, 0, stream>>>(tp, coords, vdirs, wpk,
                                    db1, db2, db3, cb1, cb2, cb3,
                                    (float*)d_out);
}